// Round 1
// baseline (87.921 us; speedup 1.0000x reference)
//
#include <hip/hip_runtime.h>
#include <hip/hip_bf16.h>

typedef __attribute__((ext_vector_type(4))) float  f32x4;
typedef __attribute__((ext_vector_type(8))) short  s16x8;

#define NB_    16
#define NH_    128
#define NS_    4096
#define ND_    512
#define NDPE_  64
#define NCHUNK 16
#define CHUNK_ 256
#define TS_    32
#define NSUB_  8
#define NT_    512

#define KROW_S 584            // shorts per kbuf row (576 + 8 pad) -> 1168 B (mod 128 = 16, conflict-free reads)
#define VROW_S 40             // shorts per vbuf/pbuf row (32 + 8 pad) -> 80 B

#define KBUF_OFF 0
#define VBUF_OFF (TS_ * KROW_S * 2)                  // 37376
#define PBUF_OFF (VBUF_OFF + ND_ * VROW_S * 2)       // 37376 + 40960 = 78336
#define SMEM_BYTES (PBUF_OFF + 8 * 16 * VROW_S * 2)  // + 10240 = 88576

// (1/sqrt(576)) * log2(e)
#define CL2 0.06011229337037348f

__device__ __forceinline__ unsigned short f2bf(float f) {
    unsigned u = __float_as_uint(f);
    u += 0x7FFFu + ((u >> 16) & 1u);
    return (unsigned short)(u >> 16);
}

__global__ __launch_bounds__(NT_, 2) void mla_attn(
    const float* __restrict__ q, const float* __restrict__ q_pe,
    const float* __restrict__ k, const float* __restrict__ k_pe,
    unsigned short* __restrict__ opart, float* __restrict__ mlbuf)
{
    extern __shared__ char smem[];
    unsigned short* kbuf = (unsigned short*)(smem + KBUF_OFF);  // [32][584] row-major bf16
    unsigned short* vbuf = (unsigned short*)(smem + VBUF_OFF);  // [512][40] transposed V bf16
    unsigned short* pbuf = (unsigned short*)(smem + PBUF_OFF);  // 8 waves x [16][40] P bf16

    const int chunk = blockIdx.x, b = blockIdx.y;
    const int tid = threadIdx.x;
    const int wv  = tid >> 6;
    const int l   = tid & 63;
    const int l16 = l & 15;
    const int lq  = l >> 4;

    f32x4 acc[32];
    #pragma unroll
    for (int i = 0; i < 32; ++i) acc[i] = (f32x4)0.0f;
    float m2[4]   = {-1e30f, -1e30f, -1e30f, -1e30f};
    float lsum[4] = {0.f, 0.f, 0.f, 0.f};

    const int sl   = tid >> 4;   // staging row 0..31
    const int ln16 = tid & 15;

    const float* qrow   = q    + (size_t)(b*NH_ + wv*16 + l16) * ND_;
    const float* qperow = q_pe + (size_t)(b*NH_ + wv*16 + l16) * NDPE_;

    unsigned short* prow = pbuf + wv * 16 * VROW_S;

    for (int t = 0; t < NSUB_; ++t) {
        // ---------------- stage K sub-tile (f32 -> bf16) ----------------
        {
            const int sg = chunk*CHUNK_ + t*TS_ + sl;
            const float* krow   = k    + (size_t)(b*NS_ + sg) * ND_;
            const float* kperow = k_pe + (size_t)(b*NS_ + sg) * NDPE_;
            #pragma unroll
            for (int i = 0; i < 9; ++i) {
                const int d0 = ln16*4 + i*64;
                f32x4 v;
                if (i < 8) v = *(const f32x4*)(krow + d0);
                else       v = *(const f32x4*)(kperow + (d0 - ND_));
                const unsigned short b0 = f2bf(v.x), b1 = f2bf(v.y),
                                     b2 = f2bf(v.z), b3 = f2bf(v.w);
                unsigned* kp = (unsigned*)&kbuf[sl*KROW_S + d0];
                kp[0] = (unsigned)b0 | ((unsigned)b1 << 16);
                kp[1] = (unsigned)b2 | ((unsigned)b3 << 16);
                if (i < 8) {  // transposed V copy (d < 512 only)
                    vbuf[(d0+0)*VROW_S + sl] = b0;
                    vbuf[(d0+1)*VROW_S + sl] = b1;
                    vbuf[(d0+2)*VROW_S + sl] = b2;
                    vbuf[(d0+3)*VROW_S + sl] = b3;
                }
            }
        }
        __syncthreads();

        // ---------------- QK^T : scores[16h x 32s] per wave ----------------
        f32x4 sc0 = (f32x4)0.0f, sc1 = (f32x4)0.0f;
        #pragma unroll
        for (int kk = 0; kk < 18; ++kk) {
            const int d0 = kk*32 + lq*8;
            f32x4 qa, qb;
            if (kk < 16) {
                qa = *(const f32x4*)(qrow + d0);
                qb = *(const f32x4*)(qrow + d0 + 4);
            } else {
                qa = *(const f32x4*)(qperow + (d0 - ND_));
                qb = *(const f32x4*)(qperow + (d0 - ND_ + 4));
            }
            s16x8 af;
            {
                union { unsigned u[4]; s16x8 s; } w;
                w.u[0] = (unsigned)f2bf(qa.x) | ((unsigned)f2bf(qa.y) << 16);
                w.u[1] = (unsigned)f2bf(qa.z) | ((unsigned)f2bf(qa.w) << 16);
                w.u[2] = (unsigned)f2bf(qb.x) | ((unsigned)f2bf(qb.y) << 16);
                w.u[3] = (unsigned)f2bf(qb.z) | ((unsigned)f2bf(qb.w) << 16);
                af = w.s;
            }
            const s16x8 bf0 = *(const s16x8*)&kbuf[(l16     )*KROW_S + d0];
            const s16x8 bf1 = *(const s16x8*)&kbuf[(l16 + 16)*KROW_S + d0];
            sc0 = __builtin_amdgcn_mfma_f32_16x16x32_bf16(af, bf0, sc0, 0, 0, 0);
            sc1 = __builtin_amdgcn_mfma_f32_16x16x32_bf16(af, bf1, sc1, 0, 0, 0);
        }

        // ---------------- online softmax (base-2, scale folded) ----------------
        float alpha[4];
        #pragma unroll
        for (int r = 0; r < 4; ++r) {
            float mx = fmaxf(sc0[r], sc1[r]);
            mx = fmaxf(mx, __shfl_xor(mx, 1));
            mx = fmaxf(mx, __shfl_xor(mx, 2));
            mx = fmaxf(mx, __shfl_xor(mx, 4));
            mx = fmaxf(mx, __shfl_xor(mx, 8));
            const float mn = fmaxf(m2[r], mx * CL2);
            const float al = exp2f(m2[r] - mn);
            const float p0 = exp2f(fmaf(sc0[r], CL2, -mn));
            const float p1 = exp2f(fmaf(sc1[r], CL2, -mn));
            float sm = p0 + p1;
            sm += __shfl_xor(sm, 1);
            sm += __shfl_xor(sm, 2);
            sm += __shfl_xor(sm, 4);
            sm += __shfl_xor(sm, 8);
            lsum[r] = al * lsum[r] + sm;
            m2[r] = mn;
            alpha[r] = al;
            prow[(lq*4 + r)*VROW_S + l16]      = f2bf(p0);
            prow[(lq*4 + r)*VROW_S + 16 + l16] = f2bf(p1);
        }
        #pragma unroll
        for (int nf = 0; nf < 32; ++nf) {
            acc[nf][0] *= alpha[0];
            acc[nf][1] *= alpha[1];
            acc[nf][2] *= alpha[2];
            acc[nf][3] *= alpha[3];
        }
        // P writes are cross-lane consumed below: drain LDS, pin order
        asm volatile("s_waitcnt lgkmcnt(0)" ::: "memory");
        __builtin_amdgcn_sched_barrier(0);

        // ---------------- PV : acc[16h x 512d] += P[16x32] * V[32x512] ----------------
        const s16x8 pf = *(const s16x8*)&prow[l16*VROW_S + lq*8];
        #pragma unroll
        for (int nf = 0; nf < 32; ++nf) {
            const s16x8 vf = *(const s16x8*)&vbuf[(nf*16 + l16)*VROW_S + lq*8];
            acc[nf] = __builtin_amdgcn_mfma_f32_16x16x32_bf16(pf, vf, acc[nf], 0, 0, 0);
        }
        __syncthreads();
    }

    // ---------------- write partials (unnormalized O in bf16, + m,l) ----------------
    const size_t obase = (size_t)(b*NCHUNK + chunk) * NH_ * ND_;
    #pragma unroll
    for (int nf = 0; nf < 32; ++nf) {
        #pragma unroll
        for (int r = 0; r < 4; ++r) {
            const int h = wv*16 + lq*4 + r;
            const int d = nf*16 + l16;
            opart[obase + (size_t)h*ND_ + d] = f2bf(acc[nf][r]);
        }
    }
    if (l16 == 0) {
        #pragma unroll
        for (int r = 0; r < 4; ++r) {
            const int h = wv*16 + lq*4 + r;
            const int idx = (b*NCHUNK + chunk)*NH_ + h;
            mlbuf[2*idx]   = m2[r];
            mlbuf[2*idx+1] = lsum[r];
        }
    }
}

__global__ __launch_bounds__(128) void mla_combine(
    const unsigned short* __restrict__ opart, const float* __restrict__ mlbuf,
    float* __restrict__ out)
{
    const int bh = blockIdx.x;
    const int b = bh >> 7, h = bh & 127;
    const int tid = threadIdx.x;

    float mv[NCHUNK], lv[NCHUNK];
    float m = -1e30f;
    #pragma unroll
    for (int c = 0; c < NCHUNK; ++c) {
        const int idx = (b*NCHUNK + c)*NH_ + h;
        mv[c] = mlbuf[2*idx];
        lv[c] = mlbuf[2*idx+1];
        m = fmaxf(m, mv[c]);
    }
    float L = 0.f, w[NCHUNK];
    #pragma unroll
    for (int c = 0; c < NCHUNK; ++c) { w[c] = exp2f(mv[c] - m); L += w[c]*lv[c]; }
    const float inv = 1.0f / L;

    const int d0 = tid * 4;
    float a0 = 0.f, a1 = 0.f, a2 = 0.f, a3 = 0.f;
    #pragma unroll
    for (int c = 0; c < NCHUNK; ++c) {
        const unsigned short* p = opart + (((size_t)(b*NCHUNK + c)*NH_ + h)*ND_ + d0);
        const unsigned u0 = *(const unsigned*)(p);
        const unsigned u1 = *(const unsigned*)(p + 2);
        a0 += w[c] * __uint_as_float((u0 & 0xffffu) << 16);
        a1 += w[c] * __uint_as_float(u0 & 0xffff0000u);
        a2 += w[c] * __uint_as_float((u1 & 0xffffu) << 16);
        a3 += w[c] * __uint_as_float(u1 & 0xffff0000u);
    }
    f32x4 res;
    res.x = a0 * inv; res.y = a1 * inv; res.z = a2 * inv; res.w = a3 * inv;
    *(f32x4*)(out + ((size_t)(b*NH_ + h)*ND_ + d0)) = res;
}

extern "C" void kernel_launch(void* const* d_in, const int* in_sizes, int n_in,
                              void* d_out, int out_size, void* d_ws, size_t ws_size,
                              hipStream_t stream) {
    const float* q    = (const float*)d_in[0];
    const float* q_pe = (const float*)d_in[1];
    const float* k    = (const float*)d_in[2];
    const float* k_pe = (const float*)d_in[3];

    unsigned short* opart = (unsigned short*)d_ws;
    float* mlbuf = (float*)((char*)d_ws + (size_t)NB_*NCHUNK*NH_*ND_*sizeof(unsigned short));

    mla_attn<<<dim3(NCHUNK, NB_), NT_, SMEM_BYTES, stream>>>(q, q_pe, k, k_pe, opart, mlbuf);
    mla_combine<<<NB_*NH_, 128, 0, stream>>>(opart, mlbuf, (float*)d_out);
}